// Round 15
// baseline (580.513 us; speedup 1.0000x reference)
//
#include <hip/hip_runtime.h>
#include <hip/hip_bf16.h>
#include <math.h>

#define NN 50000
#define NE 800000
#define FIN 128
#define FOUT 256
#define EPSF 1e-5f
#define NCHUNK 196  // ceil(NN/256)

typedef __bf16 bf16x8 __attribute__((ext_vector_type(8)));
typedef __bf16 bf16x4 __attribute__((ext_vector_type(4)));
typedef __bf16 bf16x2 __attribute__((ext_vector_type(2)));
typedef float f32x4 __attribute__((ext_vector_type(4)));
typedef _Float16 f16x8 __attribute__((ext_vector_type(8)));
typedef unsigned int u32x4 __attribute__((ext_vector_type(4)));

// ---------------------------------------------------------------------------
// Fused prep: cvt x->(bf16, wid-scaled bf16, fp16) + all weight packing.
// ---------------------------------------------------------------------------
__device__ __forceinline__ void prep_b_body(const float* __restrict__ B,
                                            __bf16* __restrict__ frag, int K, int bid, int t) {
    int idx = bid * 256 + t;
    if (idx >= K * 256) return;
    int i = idx & 7, l = (idx >> 3) & 63, ct = (idx >> 9) & 15, kk = idx >> 13;
    int k = kk * 32 + (l >> 4) * 8 + i;
    int c = ct * 16 + (l & 15);
    frag[idx] = (__bf16)B[k * 256 + c];
}

__global__ void prep_all_kernel(
    const float* __restrict__ x, const float* __restrict__ wid,
    __bf16* __restrict__ xbf, __bf16* __restrict__ xw, _Float16* __restrict__ xh,
    const float* __restrict__ m1w1, const float* __restrict__ m2w1, _Float16* __restrict__ efrag,
    const float* __restrict__ fc1w, __bf16* __restrict__ bfrag1,
    const float* __restrict__ fc2w, __bf16* __restrict__ bfrag2,
    const float* __restrict__ resw, __bf16* __restrict__ bfragR)
{
    int b = blockIdx.x, t = threadIdx.x;
    if (b < 3125) {
        int idx = b * 256 + t;
        if (idx >= NN * FIN / 8) return;
        float w = wid[idx >> 4];
        float4 a = ((const float4*)x)[idx * 2 + 0];
        float4 c = ((const float4*)x)[idx * 2 + 1];
        bf16x8 v = {(__bf16)a.x, (__bf16)a.y, (__bf16)a.z, (__bf16)a.w,
                    (__bf16)c.x, (__bf16)c.y, (__bf16)c.z, (__bf16)c.w};
        bf16x8 vw = {(__bf16)(w * a.x), (__bf16)(w * a.y), (__bf16)(w * a.z), (__bf16)(w * a.w),
                     (__bf16)(w * c.x), (__bf16)(w * c.y), (__bf16)(w * c.z), (__bf16)(w * c.w)};
        f16x8 vh = {(_Float16)a.x, (_Float16)a.y, (_Float16)a.z, (_Float16)a.w,
                    (_Float16)c.x, (_Float16)c.y, (_Float16)c.z, (_Float16)c.w};
        ((bf16x8*)xbf)[idx] = v;
        ((bf16x8*)xw)[idx] = vw;
        ((f16x8*)xh)[idx] = vh;
        return;
    }
    b -= 3125;
    if (b < 32) {
        int idx = b * 256 + t;
        int i = idx & 7, l = (idx >> 3) & 63, ct = (idx >> 9) & 3, kt = idx >> 11;
        int n = l & 15, kb = l >> 4;
        int k = kt * 32 + kb * 8 + i;
        int c = ct * 16 + n;
        float w = (c < 32) ? m1w1[k * 32 + c] : m2w1[k * 32 + (c - 32)];
        efrag[idx] = (_Float16)w;
        return;
    }
    b -= 32;
    if (b < 128) { prep_b_body(fc1w, bfrag1, 128, b, t); return; }
    b -= 128;
    if (b < 256) { prep_b_body(fc1w + 128 * 256, bfrag1 + 128 * 256, 256, b, t); return; }
    b -= 256;
    if (b < 256) { prep_b_body(fc2w, bfrag2, 256, b, t); return; }
    b -= 256;
    if (b < 512) { prep_b_body(fc2w + 256 * 256, bfrag2 + 256 * 256, 512, b, t); return; }
    b -= 512;
    prep_b_body(resw, bfragR, 128, b, t);
}

// ---------------------------------------------------------------------------
// CSR build: histogram, 3-kernel exclusive scan, fill (col,row) int2.
// ---------------------------------------------------------------------------
__global__ void hist_kernel(const int* __restrict__ rowi, int* __restrict__ counts) {
    int e = blockIdx.x * 256 + threadIdx.x;
    if (e < NE) atomicAdd(&counts[rowi[e]], 1);
}

__global__ void scan1_kernel(const int* __restrict__ counts, int* __restrict__ blksum) {
    __shared__ int s[256];
    int t = threadIdx.x, idx = blockIdx.x * 256 + t;
    s[t] = (idx < NN) ? counts[idx] : 0;
    __syncthreads();
    for (int off = 128; off > 0; off >>= 1) {
        if (t < off) s[t] += s[t + off];
        __syncthreads();
    }
    if (t == 0) blksum[blockIdx.x] = s[0];
}

__global__ void scan2_kernel(const int* __restrict__ blksum, int* __restrict__ blkoff) {
    __shared__ int s[256];
    int t = threadIdx.x;
    int v = (t < NCHUNK) ? blksum[t] : 0;
    s[t] = v; __syncthreads();
    for (int off = 1; off < 256; off <<= 1) {
        int xv = (t >= off) ? s[t - off] : 0;
        __syncthreads();
        s[t] += xv;
        __syncthreads();
    }
    if (t < NCHUNK) blkoff[t] = s[t] - v;  // exclusive
}

__global__ void scan3_kernel(const int* __restrict__ counts, const int* __restrict__ blkoff,
                             int* __restrict__ row_start) {
    __shared__ int s[256];
    int t = threadIdx.x, idx = blockIdx.x * 256 + t;
    int v = (idx < NN) ? counts[idx] : 0;
    s[t] = v; __syncthreads();
    for (int off = 1; off < 256; off <<= 1) {
        int xv = (t >= off) ? s[t - off] : 0;
        __syncthreads();
        s[t] += xv;
        __syncthreads();
    }
    if (idx <= NN) row_start[idx] = s[t] - v + blkoff[blockIdx.x];
}

__global__ void fill_kernel(const int* __restrict__ rowi, const int* __restrict__ coli,
                            const int* __restrict__ row_start, int* __restrict__ cursor,
                            int2* __restrict__ perm) {
    int e = blockIdx.x * 256 + threadIdx.x;
    if (e >= NE) return;
    int r = rowi[e];
    int p = row_start[r] + atomicAdd(&cursor[r], 1);
    perm[p] = make_int2(coli[e], r);
}

// ---------------------------------------------------------------------------
// Edge MLP via fp16 MFMA over CSR-ordered edges (packed-half abs-diff).
// ---------------------------------------------------------------------------
__global__ __launch_bounds__(256) void edge_mlp_mfma(
    const _Float16* __restrict__ x, const int2* __restrict__ perm,
    const _Float16* __restrict__ fragbuf,
    const float* __restrict__ b1a, const float* __restrict__ w2a, const float* __restrict__ b2a,
    const float* __restrict__ b1b, const float* __restrict__ w2b, const float* __restrict__ b2b,
    float2* __restrict__ v12)
{
    int lane = threadIdx.x & 63;
    int gwave = (blockIdx.x * 256 + threadIdx.x) >> 6;
    int nwaves = (gridDim.x * 256) >> 6;

    f16x8 bfrag[4][4];
    const f16x8* fb = (const f16x8*)fragbuf;
#pragma unroll
    for (int kt = 0; kt < 4; kt++)
#pragma unroll
        for (int ct = 0; ct < 4; ct++)
            bfrag[kt][ct] = fb[(kt * 4 + ct) * 64 + lane];

    int n = lane & 15;
    int kb = lane >> 4;
    float b1c[4], w2c[4];
#pragma unroll
    for (int ct = 0; ct < 4; ct++) {
        int c = ct * 16 + n;
        b1c[ct] = (c < 32) ? b1a[c] : b1b[c - 32];
        w2c[ct] = (c < 32) ? w2a[c] : w2b[c - 32];
    }
    float bias2a = b2a[0], bias2b = b2b[0];
    const u32x4 amask = {0x7FFF7FFFu, 0x7FFF7FFFu, 0x7FFF7FFFu, 0x7FFF7FFFu};

    const int ngroups = NE / 16;
    for (int g = gwave; g < ngroups; g += nwaves) {
        int2 pe = perm[g * 16 + n];
        const _Float16* xr = x + (size_t)pe.y * FIN + kb * 8;
        const _Float16* xc = x + (size_t)pe.x * FIN + kb * 8;
        f32x4 acc[4] = {{0.f, 0.f, 0.f, 0.f}, {0.f, 0.f, 0.f, 0.f},
                        {0.f, 0.f, 0.f, 0.f}, {0.f, 0.f, 0.f, 0.f}};
#pragma unroll
        for (int kt = 0; kt < 4; kt++) {
            f16x8 a = *(const f16x8*)(xr + kt * 32);
            f16x8 c = *(const f16x8*)(xc + kt * 32);
            f16x8 d = a - c;
            u32x4 db = __builtin_bit_cast(u32x4, d) & amask;
            f16x8 af = __builtin_bit_cast(f16x8, db);
#pragma unroll
            for (int ct = 0; ct < 4; ct++)
                acc[ct] = __builtin_amdgcn_mfma_f32_16x16x32_f16(af, bfrag[kt][ct], acc[ct], 0, 0, 0);
        }
        float p1[4], p2[4];
#pragma unroll
        for (int r = 0; r < 4; r++) {
            float h0 = fmaxf(acc[0][r] + b1c[0], 0.f) * w2c[0];
            float h1 = fmaxf(acc[1][r] + b1c[1], 0.f) * w2c[1];
            float h2 = fmaxf(acc[2][r] + b1c[2], 0.f) * w2c[2];
            float h3 = fmaxf(acc[3][r] + b1c[3], 0.f) * w2c[3];
            p1[r] = h0 + h1;
            p2[r] = h2 + h3;
        }
#pragma unroll
        for (int off = 1; off < 16; off <<= 1)
#pragma unroll
            for (int r = 0; r < 4; r++) {
                p1[r] += __shfl_xor(p1[r], off, 64);
                p2[r] += __shfl_xor(p2[r], off, 64);
            }
        if (n == 0) {
#pragma unroll
            for (int r = 0; r < 4; r++) {
                int p = g * 16 + kb * 4 + r;
                v12[p] = make_float2(1.f / (1.f + expf(-(p1[r] + bias2a))),
                                     1.f / (1.f + expf(-(p2[r] + bias2b))));
            }
        }
    }
}

// ---------------------------------------------------------------------------
// spmm: one wave per node; 8x-unrolled gather loop.
// ---------------------------------------------------------------------------
__global__ __launch_bounds__(256) void spmm1_kernel(
    const __bf16* __restrict__ x, const int2* __restrict__ perm,
    const float2* __restrict__ v12, const int* __restrict__ row_start,
    __bf16* __restrict__ agg)
{
    int lane = threadIdx.x & 63;
    int i = blockIdx.x * 4 + (threadIdx.x >> 6);
    if (i >= NN) return;
    int f0 = lane * 2;
    float a1x = 0, a1y = 0, a2x = 0, a2y = 0;
    int p0 = row_start[i], p1 = row_start[i + 1];
    int p = p0;
    for (; p + 8 <= p1; p += 8) {
        int cc[8]; float2 vv[8]; bf16x2 ff[8];
#pragma unroll
        for (int u = 0; u < 8; u++) { cc[u] = perm[p + u].x; vv[u] = v12[p + u]; }
#pragma unroll
        for (int u = 0; u < 8; u++)
            ff[u] = *(const bf16x2*)(x + (size_t)cc[u] * FIN + f0);
#pragma unroll
        for (int u = 0; u < 8; u++) {
            float fx = (float)ff[u][0], fy = (float)ff[u][1];
            a1x += vv[u].x * fx; a1y += vv[u].x * fy;
            a2x += vv[u].y * fx; a2y += vv[u].y * fy;
        }
    }
    for (; p + 4 <= p1; p += 4) {
        int cc[4]; float2 vv[4]; bf16x2 ff[4];
#pragma unroll
        for (int u = 0; u < 4; u++) { cc[u] = perm[p + u].x; vv[u] = v12[p + u]; }
#pragma unroll
        for (int u = 0; u < 4; u++)
            ff[u] = *(const bf16x2*)(x + (size_t)cc[u] * FIN + f0);
#pragma unroll
        for (int u = 0; u < 4; u++) {
            float fx = (float)ff[u][0], fy = (float)ff[u][1];
            a1x += vv[u].x * fx; a1y += vv[u].x * fy;
            a2x += vv[u].y * fx; a2y += vv[u].y * fy;
        }
    }
    for (; p < p1; p++) {
        int c = perm[p].x;
        float2 vv = v12[p];
        bf16x2 f = *(const bf16x2*)(x + (size_t)c * FIN + f0);
        float fx = (float)f[0], fy = (float)f[1];
        a1x += vv.x * fx; a1y += vv.x * fy;
        a2x += vv.y * fx; a2y += vv.y * fy;
    }
    __bf16* ag = agg + (size_t)i * 256;
    *(bf16x2*)(ag + f0) = (bf16x2){(__bf16)a1x, (__bf16)a1y};
    *(bf16x2*)(ag + FIN + f0) = (bf16x2){(__bf16)a2x, (__bf16)a2y};
}

__global__ __launch_bounds__(256) void spmm2_kernel(
    const __bf16* __restrict__ h, const int2* __restrict__ perm,
    const float2* __restrict__ v12, const int* __restrict__ row_start,
    __bf16* __restrict__ agg)
{
    int lane = threadIdx.x & 63;
    int i = blockIdx.x * 4 + (threadIdx.x >> 6);
    if (i >= NN) return;
    int f0 = lane * 4;
    float s1x = 0, s1y = 0, s1z = 0, s1w = 0, s2x = 0, s2y = 0, s2z = 0, s2w = 0;
    int p0 = row_start[i], p1 = row_start[i + 1];
    int p = p0;
    for (; p + 8 <= p1; p += 8) {
        int cc[8]; float2 vv[8]; bf16x4 ff[8];
#pragma unroll
        for (int u = 0; u < 8; u++) { cc[u] = perm[p + u].x; vv[u] = v12[p + u]; }
#pragma unroll
        for (int u = 0; u < 8; u++)
            ff[u] = *(const bf16x4*)(h + (size_t)cc[u] * FOUT + f0);
#pragma unroll
        for (int u = 0; u < 8; u++) {
            float fx = (float)ff[u][0], fy = (float)ff[u][1];
            float fz = (float)ff[u][2], fw = (float)ff[u][3];
            s1x += vv[u].x * fx; s1y += vv[u].x * fy; s1z += vv[u].x * fz; s1w += vv[u].x * fw;
            s2x += vv[u].y * fx; s2y += vv[u].y * fy; s2z += vv[u].y * fz; s2w += vv[u].y * fw;
        }
    }
    for (; p + 4 <= p1; p += 4) {
        int cc[4]; float2 vv[4]; bf16x4 ff[4];
#pragma unroll
        for (int u = 0; u < 4; u++) { cc[u] = perm[p + u].x; vv[u] = v12[p + u]; }
#pragma unroll
        for (int u = 0; u < 4; u++)
            ff[u] = *(const bf16x4*)(h + (size_t)cc[u] * FOUT + f0);
#pragma unroll
        for (int u = 0; u < 4; u++) {
            float fx = (float)ff[u][0], fy = (float)ff[u][1];
            float fz = (float)ff[u][2], fw = (float)ff[u][3];
            s1x += vv[u].x * fx; s1y += vv[u].x * fy; s1z += vv[u].x * fz; s1w += vv[u].x * fw;
            s2x += vv[u].y * fx; s2y += vv[u].y * fy; s2z += vv[u].y * fz; s2w += vv[u].y * fw;
        }
    }
    for (; p < p1; p++) {
        int c = perm[p].x;
        float2 vv = v12[p];
        bf16x4 f = *(const bf16x4*)(h + (size_t)c * FOUT + f0);
        float fx = (float)f[0], fy = (float)f[1], fz = (float)f[2], fw = (float)f[3];
        s1x += vv.x * fx; s1y += vv.x * fy; s1z += vv.x * fz; s1w += vv.x * fw;
        s2x += vv.y * fx; s2y += vv.y * fy; s2z += vv.y * fz; s2w += vv.y * fw;
    }
    __bf16* ag = agg + (size_t)i * 512;
    *(bf16x4*)(ag + f0) = (bf16x4){(__bf16)s1x, (__bf16)s1y, (__bf16)s1z, (__bf16)s1w};
    *(bf16x4*)(ag + FOUT + f0) = (bf16x4){(__bf16)s2x, (__bf16)s2y, (__bf16)s2z, (__bf16)s2w};
}

// ---------------------------------------------------------------------------
// Register-resident-B GEMM (edge-MLP structure): each wave owns ONE 16-col
// fragment slice; B (NK x 4 VGPR) loaded ONCE from the L2-warm frag buffer.
// Zero LDS, zero barriers, fully-unrolled K (constant breg indices) -> the
// A-stream pipelines freely. Block = 4 waves x 48 rows = 192-row tile.
// Grid = 16 col-slices x NRG row-groups; bid = cq*NRG + rgrp with NRG%8==0
// so bid&7 = rgrp&7: all 16 col-slices of a row-group share an XCD (L2 reuse
// of the redundant A reads, validated round 14). BN stats in regs -> one
// global atomic per lane at kernel end.
// ---------------------------------------------------------------------------
template<int NKA, int NKB, int NRG>
__device__ __forceinline__ void gemm_regB_core(
    const __bf16* __restrict__ Aa, const __bf16* __restrict__ Ab,
    const __bf16* __restrict__ Bfrag,
    const float* __restrict__ bias, __bf16* __restrict__ C, int M,
    float* __restrict__ colsum, float* __restrict__ colsq, int bid, int t)
{
    constexpr int NK = NKA + NKB;
    constexpr int KA = NKA * 32;
    constexpr int KB = NKB * 32;
    int lane = t & 63, w = t >> 6;
    int n = lane & 15, kb = lane >> 4;
    int cq = bid / NRG, rgrp = bid % NRG;

    bf16x8 breg[NK];
#pragma unroll
    for (int kk = 0; kk < NK; kk++)
        breg[kk] = *(const bf16x8*)(Bfrag + ((size_t)(kk * 16 + cq) * 64 + lane) * 8);
    float bv = bias ? bias[cq * 16 + n] : 0.f;
    int col = cq * 16 + n;

    float psum = 0.f, psq = 0.f;
    int ntiles = (M + 191) / 192;

    for (int tile = rgrp; tile < ntiles; tile += NRG) {
        int rowbase = tile * 192 + w * 48;
        const __bf16 *pA[3], *pB[3];
#pragma unroll
        for (int f = 0; f < 3; f++) {
            int r = rowbase + f * 16 + n; if (r > M - 1) r = M - 1;
            pA[f] = Aa + (size_t)r * KA + kb * 8;
            pB[f] = (NKB > 0) ? (Ab + (size_t)r * KB + kb * 8) : pA[f];
        }
        f32x4 acc[3];
#pragma unroll
        for (int f = 0; f < 3; f++) acc[f] = (f32x4){0.f, 0.f, 0.f, 0.f};

#pragma unroll
        for (int kk = 0; kk < NKA; kk++)
#pragma unroll
            for (int f = 0; f < 3; f++) {
                bf16x8 a = *(const bf16x8*)(pA[f] + kk * 32);
                acc[f] = __builtin_amdgcn_mfma_f32_16x16x32_bf16(a, breg[kk], acc[f], 0, 0, 0);
            }
#pragma unroll
        for (int kk = 0; kk < NKB; kk++)
#pragma unroll
            for (int f = 0; f < 3; f++) {
                bf16x8 a = *(const bf16x8*)(pB[f] + kk * 32);
                acc[f] = __builtin_amdgcn_mfma_f32_16x16x32_bf16(a, breg[NKA + kk], acc[f], 0, 0, 0);
            }

#pragma unroll
        for (int f = 0; f < 3; f++) {
            int rbase = rowbase + f * 16 + kb * 4;
#pragma unroll
            for (int r = 0; r < 4; r++) {
                int gm = rbase + r;
                if (gm < M) {
                    float v = acc[f][r] + bv;
                    C[(size_t)gm * 256 + col] = (__bf16)v;
                    psum += v; psq += v * v;
                }
            }
        }
    }

    if (colsum) {
        psum += __shfl_xor(psum, 16, 64); psq += __shfl_xor(psq, 16, 64);
        psum += __shfl_xor(psum, 32, 64); psq += __shfl_xor(psq, 32, 64);
        if (kb == 0) {
            atomicAdd(&colsum[col], psum);
            atomicAdd(&colsq[col], psq);
        }
    }
}

template<int NKA, int NKB, int RNKA>
__global__ __launch_bounds__(256, 3) void gemm_regB(
    const __bf16* __restrict__ Aa, const __bf16* __restrict__ Ab,
    const __bf16* __restrict__ Bfrag,
    const float* __restrict__ bias, __bf16* __restrict__ C, int M,
    float* __restrict__ colsum, float* __restrict__ colsq,
    const __bf16* __restrict__ Ra, const __bf16* __restrict__ RBfrag,
    __bf16* __restrict__ RC)
{
    int bid = blockIdx.x, t = threadIdx.x;
    if (bid >= 1024) {                    // fused res GEMM: 512 blocks, NRG=32
        if constexpr (RNKA > 0)
            gemm_regB_core<RNKA, 0, 32>(Ra, nullptr, RBfrag, nullptr, RC, M,
                                        nullptr, nullptr, bid - 1024, t);
        return;
    }
    gemm_regB_core<NKA, NKB, 64>(Aa, Ab, Bfrag, bias, C, M, colsum, colsq, bid, t);
}

// ---------------------------------------------------------------------------
// BN apply (+relu) bf16->bf16 (plain + wid-scaled), and final BN+res+relu.
// ---------------------------------------------------------------------------
__device__ __forceinline__ float bn1c(float v, float s, float q, float g, float b) {
    const float invn = 1.0f / (float)NN;
    float mu = s * invn;
    float var = q * invn - mu * mu;
    float r = rsqrtf(var + EPSF);
    return (v - mu) * r * g + b;
}

__global__ __launch_bounds__(256) void bn_relu_kernel(
    const __bf16* __restrict__ h, const float* __restrict__ stats,
    const float* __restrict__ g, const float* __restrict__ b,
    const float* __restrict__ wid,
    __bf16* __restrict__ o, __bf16* __restrict__ ow)
{
    size_t idx = (size_t)blockIdx.x * 256 + threadIdx.x;
    int j = ((int)idx & 31) * 8;
    float wv = wid[idx >> 5];
    bf16x8 v = ((const bf16x8*)h)[idx];
    bf16x8 r, rw;
#pragma unroll
    for (int u = 0; u < 8; u++) {
        float val = fmaxf(bn1c((float)v[u], stats[j + u], stats[256 + j + u], g[j + u], b[j + u]), 0.f);
        r[u] = (__bf16)val;
        rw[u] = (__bf16)(wv * val);
    }
    ((bf16x8*)o)[idx] = r;
    ((bf16x8*)ow)[idx] = rw;
}

__global__ __launch_bounds__(256) void final_kernel(
    const __bf16* __restrict__ h2, const float* __restrict__ stats,
    const float* __restrict__ g, const float* __restrict__ b,
    const __bf16* __restrict__ resb, float* __restrict__ o)
{
    size_t idx = (size_t)blockIdx.x * 256 + threadIdx.x;
    int j = ((int)idx & 31) * 8;
    bf16x8 v = ((const bf16x8*)h2)[idx];
    bf16x8 rr = ((const bf16x8*)resb)[idx];
    float r[8];
#pragma unroll
    for (int u = 0; u < 8; u++)
        r[u] = fmaxf(bn1c((float)v[u], stats[j + u], stats[256 + j + u], g[j + u], b[j + u]) + (float)rr[u], 0.f);
    float4 o0 = {r[0], r[1], r[2], r[3]}, o1 = {r[4], r[5], r[6], r[7]};
    ((float4*)o)[idx * 2 + 0] = o0;
    ((float4*)o)[idx * 2 + 1] = o1;
}

// ---------------------------------------------------------------------------
extern "C" void kernel_launch(void* const* d_in, const int* in_sizes, int n_in,
                              void* d_out, int out_size, void* d_ws, size_t ws_size,
                              hipStream_t stream)
{
    (void)in_sizes; (void)n_in; (void)out_size; (void)ws_size;
    const float* x    = (const float*)d_in[0];
    const float* wid  = (const float*)d_in[1];
    const int*   widx = (const int*)d_in[2];
    const float* m1w1 = (const float*)d_in[4];
    const float* m1b1 = (const float*)d_in[5];
    const float* m1w2 = (const float*)d_in[6];
    const float* m1b2 = (const float*)d_in[7];
    const float* m2w1 = (const float*)d_in[8];
    const float* m2b1 = (const float*)d_in[9];
    const float* m2w2 = (const float*)d_in[10];
    const float* m2b2 = (const float*)d_in[11];
    const float* fc1w = (const float*)d_in[12];
    const float* fc1b = (const float*)d_in[13];
    const float* bn1g = (const float*)d_in[14];
    const float* bn1b = (const float*)d_in[15];
    const float* fc2w = (const float*)d_in[16];
    const float* fc2b = (const float*)d_in[17];
    const float* bn2g = (const float*)d_in[18];
    const float* bn2b = (const float*)d_in[19];
    const float* resw = (const float*)d_in[20];
    float* out = (float*)d_out;

    char* ws = (char*)d_ws;
    __bf16* xbf   = (__bf16*)(ws);                    // 12.8 MB
    __bf16* xw    = (__bf16*)(ws + 12800000);         // 12.8 MB (wid ⊙ x)
    int2*   perm  = (int2*)(ws + 25600000);           // 6.4 MB
    float2* v12   = (float2*)(ws + 32000000);         // 6.4 MB
    __bf16* agg1s = (__bf16*)(ws + 38400000);         // [NN,256] 25.6 MB
    __bf16* agg2s = (__bf16*)(ws + 64000000);         // [NN,512] 51.2 MB
    __bf16* h1    = (__bf16*)(ws + 115200000);        // 25.6 MB (h2 overlay)
    __bf16* h2    = h1;
    __bf16* hbn   = (__bf16*)(ws + 140800000);        // 25.6 MB
    __bf16* hw    = (__bf16*)(ws + 166400000);        // 25.6 MB (wid ⊙ hbn)
    __bf16* resb  = (__bf16*)(ws + 192000000);        // 25.6 MB
    const size_t offS = 217600000;
    int* row_start = (int*)(ws + offS);               // 200064 B
    int* cursor    = (int*)(ws + offS + 200064);      // 200064 B
    int* blksum    = (int*)(ws + offS + 400128);
    int* blkoff    = (int*)(ws + offS + 401152);
    float* stats   = (float*)(ws + offS + 402176);    // 1024 floats
    _Float16* efrag = (_Float16*)(ws + offS + 406272);  // 16 KB
    __bf16* bfrag1 = (__bf16*)(ws + offS + 422656);   // 384*256*2 = 196608
    __bf16* bfrag2 = (__bf16*)(ws + offS + 619264);   // 768*256*2 = 393216
    __bf16* bfragR = (__bf16*)(ws + offS + 1012480);  // 128*256*2 = 65536
    _Float16* xh   = (_Float16*)(ws + offS + 1078016); // 12.8 MB fp16 x

    dim3 b256(256);

    // 0) fused conversions + weight packing (1 dispatch)
    prep_all_kernel<<<3125 + 32 + 128 + 256 + 256 + 512 + 128, b256, 0, stream>>>(
        x, wid, xbf, xw, xh, m1w1, m2w1, efrag, fc1w, bfrag1, fc2w, bfrag2, resw, bfragR);

    // 1) CSR build (indices only)
    hipMemsetAsync(cursor, 0, NN * 4, stream);
    hist_kernel<<<NE / 256, b256, 0, stream>>>(widx, cursor);
    scan1_kernel<<<NCHUNK, b256, 0, stream>>>(cursor, blksum);
    scan2_kernel<<<1, b256, 0, stream>>>(blksum, blkoff);
    scan3_kernel<<<NCHUNK, b256, 0, stream>>>(cursor, blkoff, row_start);
    hipMemsetAsync(cursor, 0, NN * 4, stream);
    fill_kernel<<<NE / 256, b256, 0, stream>>>(widx, widx + NE, row_start, cursor, perm);

    // 2) edge MLP over CSR order -> v12
    edge_mlp_mfma<<<2500, b256, 0, stream>>>(xh, perm, efrag,
        m1b1, m1w2, m1b2, m2b1, m2w2, m2b2, v12);

    // 3) conv1 (+ res GEMM fused, blocks 1024..1535)
    spmm1_kernel<<<NN / 4, b256, 0, stream>>>(xbf, perm, v12, row_start, agg1s);
    hipMemsetAsync(stats, 0, 1024 * 4, stream);
    gemm_regB<4, 8, 4><<<1536, b256, 0, stream>>>(
        xw, agg1s, bfrag1, fc1b, h1, NN, stats, stats + 256,
        xbf, bfragR, resb);
    bn_relu_kernel<<<NN * FOUT / 8 / 256, b256, 0, stream>>>(h1, stats, bn1g, bn1b, wid, hbn, hw);

    // 4) conv2
    spmm2_kernel<<<NN / 4, b256, 0, stream>>>(hbn, perm, v12, row_start, agg2s);
    gemm_regB<8, 16, 0><<<1024, b256, 0, stream>>>(
        hw, agg2s, bfrag2, fc2b, h2, NN, stats + 512, stats + 768,
        nullptr, nullptr, nullptr);
    final_kernel<<<NN * FOUT / 8 / 256, b256, 0, stream>>>(h2, stats + 512, bn2g, bn2b, resb, out);
}

// Round 16
// 392.826 us; speedup vs baseline: 1.4778x; 1.4778x over previous
//
#include <hip/hip_runtime.h>
#include <hip/hip_bf16.h>
#include <math.h>

#define NN 50000
#define NE 800000
#define FIN 128
#define FOUT 256
#define EPSF 1e-5f
#define NCHUNK 196  // ceil(NN/256)

typedef __bf16 bf16x8 __attribute__((ext_vector_type(8)));
typedef __bf16 bf16x4 __attribute__((ext_vector_type(4)));
typedef __bf16 bf16x2 __attribute__((ext_vector_type(2)));
typedef float f32x4 __attribute__((ext_vector_type(4)));
typedef _Float16 f16x8 __attribute__((ext_vector_type(8)));
typedef unsigned int u32x4 __attribute__((ext_vector_type(4)));

// ---------------------------------------------------------------------------
// Fused prep: cvt x->(bf16, wid-scaled bf16, fp16) + all weight packing.
// ---------------------------------------------------------------------------
__device__ __forceinline__ void prep_b_body(const float* __restrict__ B,
                                            __bf16* __restrict__ frag, int K, int bid, int t) {
    int idx = bid * 256 + t;
    if (idx >= K * 256) return;
    int i = idx & 7, l = (idx >> 3) & 63, ct = (idx >> 9) & 15, kk = idx >> 13;
    int k = kk * 32 + (l >> 4) * 8 + i;
    int c = ct * 16 + (l & 15);
    frag[idx] = (__bf16)B[k * 256 + c];
}

__global__ void prep_all_kernel(
    const float* __restrict__ x, const float* __restrict__ wid,
    __bf16* __restrict__ xbf, __bf16* __restrict__ xw, _Float16* __restrict__ xh,
    const float* __restrict__ m1w1, const float* __restrict__ m2w1, _Float16* __restrict__ efrag,
    const float* __restrict__ fc1w, __bf16* __restrict__ bfrag1,
    const float* __restrict__ fc2w, __bf16* __restrict__ bfrag2,
    const float* __restrict__ resw, __bf16* __restrict__ bfragR)
{
    int b = blockIdx.x, t = threadIdx.x;
    if (b < 3125) {
        int idx = b * 256 + t;
        if (idx >= NN * FIN / 8) return;
        float w = wid[idx >> 4];
        float4 a = ((const float4*)x)[idx * 2 + 0];
        float4 c = ((const float4*)x)[idx * 2 + 1];
        bf16x8 v = {(__bf16)a.x, (__bf16)a.y, (__bf16)a.z, (__bf16)a.w,
                    (__bf16)c.x, (__bf16)c.y, (__bf16)c.z, (__bf16)c.w};
        bf16x8 vw = {(__bf16)(w * a.x), (__bf16)(w * a.y), (__bf16)(w * a.z), (__bf16)(w * a.w),
                     (__bf16)(w * c.x), (__bf16)(w * c.y), (__bf16)(w * c.z), (__bf16)(w * c.w)};
        f16x8 vh = {(_Float16)a.x, (_Float16)a.y, (_Float16)a.z, (_Float16)a.w,
                    (_Float16)c.x, (_Float16)c.y, (_Float16)c.z, (_Float16)c.w};
        ((bf16x8*)xbf)[idx] = v;
        ((bf16x8*)xw)[idx] = vw;
        ((f16x8*)xh)[idx] = vh;
        return;
    }
    b -= 3125;
    if (b < 32) {
        int idx = b * 256 + t;
        int i = idx & 7, l = (idx >> 3) & 63, ct = (idx >> 9) & 3, kt = idx >> 11;
        int n = l & 15, kb = l >> 4;
        int k = kt * 32 + kb * 8 + i;
        int c = ct * 16 + n;
        float w = (c < 32) ? m1w1[k * 32 + c] : m2w1[k * 32 + (c - 32)];
        efrag[idx] = (_Float16)w;
        return;
    }
    b -= 32;
    if (b < 128) { prep_b_body(fc1w, bfrag1, 128, b, t); return; }
    b -= 128;
    if (b < 256) { prep_b_body(fc1w + 128 * 256, bfrag1 + 128 * 256, 256, b, t); return; }
    b -= 256;
    if (b < 256) { prep_b_body(fc2w, bfrag2, 256, b, t); return; }
    b -= 256;
    if (b < 512) { prep_b_body(fc2w + 256 * 256, bfrag2 + 256 * 256, 512, b, t); return; }
    b -= 512;
    prep_b_body(resw, bfragR, 128, b, t);
}

// ---------------------------------------------------------------------------
// CSR build: histogram, 3-kernel exclusive scan, fill (col,row) int2.
// ---------------------------------------------------------------------------
__global__ void hist_kernel(const int* __restrict__ rowi, int* __restrict__ counts) {
    int e = blockIdx.x * 256 + threadIdx.x;
    if (e < NE) atomicAdd(&counts[rowi[e]], 1);
}

__global__ void scan1_kernel(const int* __restrict__ counts, int* __restrict__ blksum) {
    __shared__ int s[256];
    int t = threadIdx.x, idx = blockIdx.x * 256 + t;
    s[t] = (idx < NN) ? counts[idx] : 0;
    __syncthreads();
    for (int off = 128; off > 0; off >>= 1) {
        if (t < off) s[t] += s[t + off];
        __syncthreads();
    }
    if (t == 0) blksum[blockIdx.x] = s[0];
}

__global__ void scan2_kernel(const int* __restrict__ blksum, int* __restrict__ blkoff) {
    __shared__ int s[256];
    int t = threadIdx.x;
    int v = (t < NCHUNK) ? blksum[t] : 0;
    s[t] = v; __syncthreads();
    for (int off = 1; off < 256; off <<= 1) {
        int xv = (t >= off) ? s[t - off] : 0;
        __syncthreads();
        s[t] += xv;
        __syncthreads();
    }
    if (t < NCHUNK) blkoff[t] = s[t] - v;  // exclusive
}

__global__ void scan3_kernel(const int* __restrict__ counts, const int* __restrict__ blkoff,
                             int* __restrict__ row_start) {
    __shared__ int s[256];
    int t = threadIdx.x, idx = blockIdx.x * 256 + t;
    int v = (idx < NN) ? counts[idx] : 0;
    s[t] = v; __syncthreads();
    for (int off = 1; off < 256; off <<= 1) {
        int xv = (t >= off) ? s[t - off] : 0;
        __syncthreads();
        s[t] += xv;
        __syncthreads();
    }
    if (idx <= NN) row_start[idx] = s[t] - v + blkoff[blockIdx.x];
}

__global__ void fill_kernel(const int* __restrict__ rowi, const int* __restrict__ coli,
                            const int* __restrict__ row_start, int* __restrict__ cursor,
                            int2* __restrict__ perm) {
    int e = blockIdx.x * 256 + threadIdx.x;
    if (e >= NE) return;
    int r = rowi[e];
    int p = row_start[r] + atomicAdd(&cursor[r], 1);
    perm[p] = make_int2(coli[e], r);
}

// ---------------------------------------------------------------------------
// Edge MLP via fp16 MFMA over CSR-ordered edges (packed-half abs-diff).
// ---------------------------------------------------------------------------
__global__ __launch_bounds__(256) void edge_mlp_mfma(
    const _Float16* __restrict__ x, const int2* __restrict__ perm,
    const _Float16* __restrict__ fragbuf,
    const float* __restrict__ b1a, const float* __restrict__ w2a, const float* __restrict__ b2a,
    const float* __restrict__ b1b, const float* __restrict__ w2b, const float* __restrict__ b2b,
    float2* __restrict__ v12)
{
    int lane = threadIdx.x & 63;
    int gwave = (blockIdx.x * 256 + threadIdx.x) >> 6;
    int nwaves = (gridDim.x * 256) >> 6;

    f16x8 bfrag[4][4];
    const f16x8* fb = (const f16x8*)fragbuf;
#pragma unroll
    for (int kt = 0; kt < 4; kt++)
#pragma unroll
        for (int ct = 0; ct < 4; ct++)
            bfrag[kt][ct] = fb[(kt * 4 + ct) * 64 + lane];

    int n = lane & 15;
    int kb = lane >> 4;
    float b1c[4], w2c[4];
#pragma unroll
    for (int ct = 0; ct < 4; ct++) {
        int c = ct * 16 + n;
        b1c[ct] = (c < 32) ? b1a[c] : b1b[c - 32];
        w2c[ct] = (c < 32) ? w2a[c] : w2b[c - 32];
    }
    float bias2a = b2a[0], bias2b = b2b[0];
    const u32x4 amask = {0x7FFF7FFFu, 0x7FFF7FFFu, 0x7FFF7FFFu, 0x7FFF7FFFu};

    const int ngroups = NE / 16;
    for (int g = gwave; g < ngroups; g += nwaves) {
        int2 pe = perm[g * 16 + n];
        const _Float16* xr = x + (size_t)pe.y * FIN + kb * 8;
        const _Float16* xc = x + (size_t)pe.x * FIN + kb * 8;
        f32x4 acc[4] = {{0.f, 0.f, 0.f, 0.f}, {0.f, 0.f, 0.f, 0.f},
                        {0.f, 0.f, 0.f, 0.f}, {0.f, 0.f, 0.f, 0.f}};
#pragma unroll
        for (int kt = 0; kt < 4; kt++) {
            f16x8 a = *(const f16x8*)(xr + kt * 32);
            f16x8 c = *(const f16x8*)(xc + kt * 32);
            f16x8 d = a - c;
            u32x4 db = __builtin_bit_cast(u32x4, d) & amask;
            f16x8 af = __builtin_bit_cast(f16x8, db);
#pragma unroll
            for (int ct = 0; ct < 4; ct++)
                acc[ct] = __builtin_amdgcn_mfma_f32_16x16x32_f16(af, bfrag[kt][ct], acc[ct], 0, 0, 0);
        }
        float p1[4], p2[4];
#pragma unroll
        for (int r = 0; r < 4; r++) {
            float h0 = fmaxf(acc[0][r] + b1c[0], 0.f) * w2c[0];
            float h1 = fmaxf(acc[1][r] + b1c[1], 0.f) * w2c[1];
            float h2 = fmaxf(acc[2][r] + b1c[2], 0.f) * w2c[2];
            float h3 = fmaxf(acc[3][r] + b1c[3], 0.f) * w2c[3];
            p1[r] = h0 + h1;
            p2[r] = h2 + h3;
        }
#pragma unroll
        for (int off = 1; off < 16; off <<= 1)
#pragma unroll
            for (int r = 0; r < 4; r++) {
                p1[r] += __shfl_xor(p1[r], off, 64);
                p2[r] += __shfl_xor(p2[r], off, 64);
            }
        if (n == 0) {
#pragma unroll
            for (int r = 0; r < 4; r++) {
                int p = g * 16 + kb * 4 + r;
                v12[p] = make_float2(1.f / (1.f + expf(-(p1[r] + bias2a))),
                                     1.f / (1.f + expf(-(p2[r] + bias2b))));
            }
        }
    }
}

// ---------------------------------------------------------------------------
// spmm: one wave per node; 8x-unrolled gather loop.
// ---------------------------------------------------------------------------
__global__ __launch_bounds__(256) void spmm1_kernel(
    const __bf16* __restrict__ x, const int2* __restrict__ perm,
    const float2* __restrict__ v12, const int* __restrict__ row_start,
    __bf16* __restrict__ agg)
{
    int lane = threadIdx.x & 63;
    int i = blockIdx.x * 4 + (threadIdx.x >> 6);
    if (i >= NN) return;
    int f0 = lane * 2;
    float a1x = 0, a1y = 0, a2x = 0, a2y = 0;
    int p0 = row_start[i], p1 = row_start[i + 1];
    int p = p0;
    for (; p + 8 <= p1; p += 8) {
        int cc[8]; float2 vv[8]; bf16x2 ff[8];
#pragma unroll
        for (int u = 0; u < 8; u++) { cc[u] = perm[p + u].x; vv[u] = v12[p + u]; }
#pragma unroll
        for (int u = 0; u < 8; u++)
            ff[u] = *(const bf16x2*)(x + (size_t)cc[u] * FIN + f0);
#pragma unroll
        for (int u = 0; u < 8; u++) {
            float fx = (float)ff[u][0], fy = (float)ff[u][1];
            a1x += vv[u].x * fx; a1y += vv[u].x * fy;
            a2x += vv[u].y * fx; a2y += vv[u].y * fy;
        }
    }
    for (; p + 4 <= p1; p += 4) {
        int cc[4]; float2 vv[4]; bf16x2 ff[4];
#pragma unroll
        for (int u = 0; u < 4; u++) { cc[u] = perm[p + u].x; vv[u] = v12[p + u]; }
#pragma unroll
        for (int u = 0; u < 4; u++)
            ff[u] = *(const bf16x2*)(x + (size_t)cc[u] * FIN + f0);
#pragma unroll
        for (int u = 0; u < 4; u++) {
            float fx = (float)ff[u][0], fy = (float)ff[u][1];
            a1x += vv[u].x * fx; a1y += vv[u].x * fy;
            a2x += vv[u].y * fx; a2y += vv[u].y * fy;
        }
    }
    for (; p < p1; p++) {
        int c = perm[p].x;
        float2 vv = v12[p];
        bf16x2 f = *(const bf16x2*)(x + (size_t)c * FIN + f0);
        float fx = (float)f[0], fy = (float)f[1];
        a1x += vv.x * fx; a1y += vv.x * fy;
        a2x += vv.y * fx; a2y += vv.y * fy;
    }
    __bf16* ag = agg + (size_t)i * 256;
    *(bf16x2*)(ag + f0) = (bf16x2){(__bf16)a1x, (__bf16)a1y};
    *(bf16x2*)(ag + FIN + f0) = (bf16x2){(__bf16)a2x, (__bf16)a2y};
}

__global__ __launch_bounds__(256) void spmm2_kernel(
    const __bf16* __restrict__ h, const int2* __restrict__ perm,
    const float2* __restrict__ v12, const int* __restrict__ row_start,
    __bf16* __restrict__ agg)
{
    int lane = threadIdx.x & 63;
    int i = blockIdx.x * 4 + (threadIdx.x >> 6);
    if (i >= NN) return;
    int f0 = lane * 4;
    float s1x = 0, s1y = 0, s1z = 0, s1w = 0, s2x = 0, s2y = 0, s2z = 0, s2w = 0;
    int p0 = row_start[i], p1 = row_start[i + 1];
    int p = p0;
    for (; p + 8 <= p1; p += 8) {
        int cc[8]; float2 vv[8]; bf16x4 ff[8];
#pragma unroll
        for (int u = 0; u < 8; u++) { cc[u] = perm[p + u].x; vv[u] = v12[p + u]; }
#pragma unroll
        for (int u = 0; u < 8; u++)
            ff[u] = *(const bf16x4*)(h + (size_t)cc[u] * FOUT + f0);
#pragma unroll
        for (int u = 0; u < 8; u++) {
            float fx = (float)ff[u][0], fy = (float)ff[u][1];
            float fz = (float)ff[u][2], fw = (float)ff[u][3];
            s1x += vv[u].x * fx; s1y += vv[u].x * fy; s1z += vv[u].x * fz; s1w += vv[u].x * fw;
            s2x += vv[u].y * fx; s2y += vv[u].y * fy; s2z += vv[u].y * fz; s2w += vv[u].y * fw;
        }
    }
    for (; p + 4 <= p1; p += 4) {
        int cc[4]; float2 vv[4]; bf16x4 ff[4];
#pragma unroll
        for (int u = 0; u < 4; u++) { cc[u] = perm[p + u].x; vv[u] = v12[p + u]; }
#pragma unroll
        for (int u = 0; u < 4; u++)
            ff[u] = *(const bf16x4*)(h + (size_t)cc[u] * FOUT + f0);
#pragma unroll
        for (int u = 0; u < 4; u++) {
            float fx = (float)ff[u][0], fy = (float)ff[u][1];
            float fz = (float)ff[u][2], fw = (float)ff[u][3];
            s1x += vv[u].x * fx; s1y += vv[u].x * fy; s1z += vv[u].x * fz; s1w += vv[u].x * fw;
            s2x += vv[u].y * fx; s2y += vv[u].y * fy; s2z += vv[u].y * fz; s2w += vv[u].y * fw;
        }
    }
    for (; p < p1; p++) {
        int c = perm[p].x;
        float2 vv = v12[p];
        bf16x4 f = *(const bf16x4*)(h + (size_t)c * FOUT + f0);
        float fx = (float)f[0], fy = (float)f[1], fz = (float)f[2], fw = (float)f[3];
        s1x += vv.x * fx; s1y += vv.x * fy; s1z += vv.x * fz; s1w += vv.x * fw;
        s2x += vv.y * fx; s2y += vv.y * fy; s2z += vv.y * fz; s2w += vv.y * fw;
    }
    __bf16* ag = agg + (size_t)i * 512;
    *(bf16x4*)(ag + f0) = (bf16x4){(__bf16)s1x, (__bf16)s1y, (__bf16)s1z, (__bf16)s1w};
    *(bf16x4*)(ag + FOUT + f0) = (bf16x4){(__bf16)s2x, (__bf16)s2y, (__bf16)s2z, (__bf16)s2w};
}

// ---------------------------------------------------------------------------
// Persistent-panel bf16 MFMA GEMM, compile-time K, bounded unroll, 12 waves.
// XCD-coscheduled panels: the 4 column-panel blocks that read the SAME rows
// land on the SAME XCD (bid&7), so the per-XCD L2 serves the redundant A
// reads. Full-K 64-col B panel staged once; barrier-free K-loop.
// ---------------------------------------------------------------------------
template<int NKA, int NKB>
__device__ __forceinline__ void gemm_core(
    const __bf16* __restrict__ Aa, const __bf16* __restrict__ Ab,
    const __bf16* __restrict__ Bfrag,
    const float* __restrict__ bias, __bf16* __restrict__ C, int M,
    float* __restrict__ colsum, float* __restrict__ colsq,
    __bf16* bs, float* lsum, float* lsq, int bid, int t)
{
    constexpr int NK = NKA + NKB;
    constexpr int KA = NKA * 32;
    constexpr int KB = NKB * 32;
    int lane = t & 63, w = t >> 6;
    // XCD-coscheduled decode: 4 panels (q) of row-group rstart share bid&7.
    int xcd = bid & 7;
    int q = (bid >> 3) & 3;
    int rstart = ((bid >> 5) << 3) | xcd;   // [0,64)
    int n = lane & 15, kb = lane >> 4;
    int ntiles = (M + 575) / 576;

    // ---- stage the full-K 64-col B panel (once) ----
    int nseg = NK * 4;
    for (int s = w; s < nseg; s += 12) {
        const __bf16* src = Bfrag + (((size_t)(s >> 2) * 16 + q * 4 + (s & 3)) * 512) + lane * 8;
        __builtin_amdgcn_global_load_lds(
            (const __attribute__((address_space(1))) void*)src,
            (__attribute__((address_space(3))) void*)(bs + s * 512),
            16, 0, 0);
    }
    float bv[4];
#pragma unroll
    for (int ct = 0; ct < 4; ct++) bv[ct] = bias ? bias[q * 64 + ct * 16 + n] : 0.f;
    __syncthreads();                      // DMA drained; panel resident

    float psum[4] = {0.f, 0.f, 0.f, 0.f}, psq[4] = {0.f, 0.f, 0.f, 0.f};

    for (int tile = rstart; tile < ntiles; tile += 64) {
        int rowbase = tile * 576 + w * 48;
        const __bf16 *pA[3], *pB[3];
#pragma unroll
        for (int f = 0; f < 3; f++) {
            int r = rowbase + f * 16 + n; if (r > M - 1) r = M - 1;
            pA[f] = Aa + (size_t)r * KA + kb * 8;
            pB[f] = (NKB > 0 && Ab) ? (Ab + (size_t)r * KB + kb * 8) : pA[f];
        }
        f32x4 acc[3][4];
#pragma unroll
        for (int f = 0; f < 3; f++)
#pragma unroll
            for (int ct = 0; ct < 4; ct++) acc[f][ct] = (f32x4){0.f, 0.f, 0.f, 0.f};

#pragma unroll 4
        for (int kk = 0; kk < NKA; kk++) {
            bf16x8 a[3];
#pragma unroll
            for (int f = 0; f < 3; f++) a[f] = *(const bf16x8*)(pA[f] + kk * 32);
            const __bf16* bbase = bs + kk * 2048 + lane * 8;
#pragma unroll
            for (int ct = 0; ct < 4; ct++) {
                bf16x8 bf = *(const bf16x8*)(bbase + ct * 512);
#pragma unroll
                for (int f = 0; f < 3; f++)
                    acc[f][ct] = __builtin_amdgcn_mfma_f32_16x16x32_bf16(a[f], bf, acc[f][ct], 0, 0, 0);
            }
        }
#pragma unroll 4
        for (int kk = 0; kk < NKB; kk++) {
            bf16x8 a[3];
#pragma unroll
            for (int f = 0; f < 3; f++) a[f] = *(const bf16x8*)(pB[f] + kk * 32);
            const __bf16* bbase = bs + (NKA + kk) * 2048 + lane * 8;
#pragma unroll
            for (int ct = 0; ct < 4; ct++) {
                bf16x8 bf = *(const bf16x8*)(bbase + ct * 512);
#pragma unroll
                for (int f = 0; f < 3; f++)
                    acc[f][ct] = __builtin_amdgcn_mfma_f32_16x16x32_bf16(a[f], bf, acc[f][ct], 0, 0, 0);
            }
        }

#pragma unroll
        for (int f = 0; f < 3; f++) {
            int rbase = rowbase + f * 16 + kb * 4;
#pragma unroll
            for (int ct = 0; ct < 4; ct++) {
                int col = q * 64 + ct * 16 + n;
#pragma unroll
                for (int r = 0; r < 4; r++) {
                    int gm = rbase + r;
                    if (gm < M) {
                        float v = acc[f][ct][r] + bv[ct];
                        C[(size_t)gm * 256 + col] = (__bf16)v;
                        psum[ct] += v; psq[ct] += v * v;
                    }
                }
            }
        }
    }

    if (colsum) {
        __syncthreads();
        if (t < 64) { lsum[t] = 0.f; lsq[t] = 0.f; }
        __syncthreads();
#pragma unroll
        for (int ct = 0; ct < 4; ct++) {
            float ps = psum[ct], pq = psq[ct];
            ps += __shfl_xor(ps, 16, 64); pq += __shfl_xor(pq, 16, 64);
            ps += __shfl_xor(ps, 32, 64); pq += __shfl_xor(pq, 32, 64);
            if (lane < 16) {
                atomicAdd(&lsum[ct * 16 + n], ps);
                atomicAdd(&lsq[ct * 16 + n], pq);
            }
        }
        __syncthreads();
        if (t < 64) {
            atomicAdd(&colsum[q * 64 + t], lsum[t]);
            atomicAdd(&colsq[q * 64 + t], lsq[t]);
        }
    }
}

template<int NKA, int NKB, int RNKA>
__global__ __launch_bounds__(768) void gemm_persist(
    const __bf16* __restrict__ Aa, const __bf16* __restrict__ Ab,
    const __bf16* __restrict__ Bfrag,
    const float* __restrict__ bias, __bf16* __restrict__ C, int M,
    float* __restrict__ colsum, float* __restrict__ colsq,
    const __bf16* __restrict__ Ra, const __bf16* __restrict__ RBfrag,
    __bf16* __restrict__ RC)
{
    constexpr int NKMAX = (NKA + NKB > RNKA) ? (NKA + NKB) : RNKA;
    __shared__ __bf16 bs[NKMAX * 2048];
    __shared__ float lsum[64], lsq[64];
    int bid = blockIdx.x, t = threadIdx.x;
    if (bid >= 256) {
        if constexpr (RNKA > 0)
            gemm_core<RNKA, 0>(Ra, nullptr, RBfrag, nullptr, RC, M,
                               nullptr, nullptr, bs, lsum, lsq, bid - 256, t);
        return;
    }
    gemm_core<NKA, NKB>(Aa, Ab, Bfrag, bias, C, M, colsum, colsq, bs, lsum, lsq, bid, t);
}

// ---------------------------------------------------------------------------
// BN apply (+relu) bf16->bf16 (plain + wid-scaled), and final BN+res+relu.
// ---------------------------------------------------------------------------
__device__ __forceinline__ float bn1c(float v, float s, float q, float g, float b) {
    const float invn = 1.0f / (float)NN;
    float mu = s * invn;
    float var = q * invn - mu * mu;
    float r = rsqrtf(var + EPSF);
    return (v - mu) * r * g + b;
}

__global__ __launch_bounds__(256) void bn_relu_kernel(
    const __bf16* __restrict__ h, const float* __restrict__ stats,
    const float* __restrict__ g, const float* __restrict__ b,
    const float* __restrict__ wid,
    __bf16* __restrict__ o, __bf16* __restrict__ ow)
{
    size_t idx = (size_t)blockIdx.x * 256 + threadIdx.x;
    int j = ((int)idx & 31) * 8;
    float wv = wid[idx >> 5];
    bf16x8 v = ((const bf16x8*)h)[idx];
    bf16x8 r, rw;
#pragma unroll
    for (int u = 0; u < 8; u++) {
        float val = fmaxf(bn1c((float)v[u], stats[j + u], stats[256 + j + u], g[j + u], b[j + u]), 0.f);
        r[u] = (__bf16)val;
        rw[u] = (__bf16)(wv * val);
    }
    ((bf16x8*)o)[idx] = r;
    ((bf16x8*)ow)[idx] = rw;
}

__global__ __launch_bounds__(256) void final_kernel(
    const __bf16* __restrict__ h2, const float* __restrict__ stats,
    const float* __restrict__ g, const float* __restrict__ b,
    const __bf16* __restrict__ resb, float* __restrict__ o)
{
    size_t idx = (size_t)blockIdx.x * 256 + threadIdx.x;
    int j = ((int)idx & 31) * 8;
    bf16x8 v = ((const bf16x8*)h2)[idx];
    bf16x8 rr = ((const bf16x8*)resb)[idx];
    float r[8];
#pragma unroll
    for (int u = 0; u < 8; u++)
        r[u] = fmaxf(bn1c((float)v[u], stats[j + u], stats[256 + j + u], g[j + u], b[j + u]) + (float)rr[u], 0.f);
    float4 o0 = {r[0], r[1], r[2], r[3]}, o1 = {r[4], r[5], r[6], r[7]};
    ((float4*)o)[idx * 2 + 0] = o0;
    ((float4*)o)[idx * 2 + 1] = o1;
}

// ---------------------------------------------------------------------------
extern "C" void kernel_launch(void* const* d_in, const int* in_sizes, int n_in,
                              void* d_out, int out_size, void* d_ws, size_t ws_size,
                              hipStream_t stream)
{
    (void)in_sizes; (void)n_in; (void)out_size; (void)ws_size;
    const float* x    = (const float*)d_in[0];
    const float* wid  = (const float*)d_in[1];
    const int*   widx = (const int*)d_in[2];
    const float* m1w1 = (const float*)d_in[4];
    const float* m1b1 = (const float*)d_in[5];
    const float* m1w2 = (const float*)d_in[6];
    const float* m1b2 = (const float*)d_in[7];
    const float* m2w1 = (const float*)d_in[8];
    const float* m2b1 = (const float*)d_in[9];
    const float* m2w2 = (const float*)d_in[10];
    const float* m2b2 = (const float*)d_in[11];
    const float* fc1w = (const float*)d_in[12];
    const float* fc1b = (const float*)d_in[13];
    const float* bn1g = (const float*)d_in[14];
    const float* bn1b = (const float*)d_in[15];
    const float* fc2w = (const float*)d_in[16];
    const float* fc2b = (const float*)d_in[17];
    const float* bn2g = (const float*)d_in[18];
    const float* bn2b = (const float*)d_in[19];
    const float* resw = (const float*)d_in[20];
    float* out = (float*)d_out;

    char* ws = (char*)d_ws;
    __bf16* xbf   = (__bf16*)(ws);                    // 12.8 MB
    __bf16* xw    = (__bf16*)(ws + 12800000);         // 12.8 MB (wid ⊙ x)
    int2*   perm  = (int2*)(ws + 25600000);           // 6.4 MB
    float2* v12   = (float2*)(ws + 32000000);         // 6.4 MB
    __bf16* agg1s = (__bf16*)(ws + 38400000);         // [NN,256] 25.6 MB
    __bf16* agg2s = (__bf16*)(ws + 64000000);         // [NN,512] 51.2 MB
    __bf16* h1    = (__bf16*)(ws + 115200000);        // 25.6 MB (h2 overlay)
    __bf16* h2    = h1;
    __bf16* hbn   = (__bf16*)(ws + 140800000);        // 25.6 MB
    __bf16* hw    = (__bf16*)(ws + 166400000);        // 25.6 MB (wid ⊙ hbn)
    __bf16* resb  = (__bf16*)(ws + 192000000);        // 25.6 MB
    const size_t offS = 217600000;
    int* row_start = (int*)(ws + offS);               // 200064 B
    int* cursor    = (int*)(ws + offS + 200064);      // 200064 B
    int* blksum    = (int*)(ws + offS + 400128);
    int* blkoff    = (int*)(ws + offS + 401152);
    float* stats   = (float*)(ws + offS + 402176);    // 1024 floats
    _Float16* efrag = (_Float16*)(ws + offS + 406272);  // 16 KB
    __bf16* bfrag1 = (__bf16*)(ws + offS + 422656);   // 384*256*2 = 196608
    __bf16* bfrag2 = (__bf16*)(ws + offS + 619264);   // 768*256*2 = 393216
    __bf16* bfragR = (__bf16*)(ws + offS + 1012480);  // 128*256*2 = 65536
    _Float16* xh   = (_Float16*)(ws + offS + 1078016); // 12.8 MB fp16 x

    dim3 b256(256);

    // 0) fused conversions + weight packing (1 dispatch)
    prep_all_kernel<<<3125 + 32 + 128 + 256 + 256 + 512 + 128, b256, 0, stream>>>(
        x, wid, xbf, xw, xh, m1w1, m2w1, efrag, fc1w, bfrag1, fc2w, bfrag2, resw, bfragR);

    // 1) CSR build (indices only)
    hipMemsetAsync(cursor, 0, NN * 4, stream);
    hist_kernel<<<NE / 256, b256, 0, stream>>>(widx, cursor);
    scan1_kernel<<<NCHUNK, b256, 0, stream>>>(cursor, blksum);
    scan2_kernel<<<1, b256, 0, stream>>>(blksum, blkoff);
    scan3_kernel<<<NCHUNK, b256, 0, stream>>>(cursor, blkoff, row_start);
    hipMemsetAsync(cursor, 0, NN * 4, stream);
    fill_kernel<<<NE / 256, b256, 0, stream>>>(widx, widx + NE, row_start, cursor, perm);

    // 2) edge MLP over CSR order -> v12
    edge_mlp_mfma<<<2500, b256, 0, stream>>>(xh, perm, efrag,
        m1b1, m1w2, m1b2, m2b1, m2w2, m2b2, v12);

    // 3) conv1 (+ res GEMM fused, blocks 256..511)
    spmm1_kernel<<<NN / 4, b256, 0, stream>>>(xbf, perm, v12, row_start, agg1s);
    hipMemsetAsync(stats, 0, 1024 * 4, stream);
    gemm_persist<4, 8, 4><<<512, dim3(768), 0, stream>>>(
        xw, agg1s, bfrag1, fc1b, h1, NN, stats, stats + 256,
        xbf, bfragR, resb);
    bn_relu_kernel<<<NN * FOUT / 8 / 256, b256, 0, stream>>>(h1, stats, bn1g, bn1b, wid, hbn, hw);

    // 4) conv2
    spmm2_kernel<<<NN / 4, b256, 0, stream>>>(hbn, perm, v12, row_start, agg2s);
    gemm_persist<8, 16, 0><<<256, dim3(768), 0, stream>>>(
        hw, agg2s, bfrag2, fc2b, h2, NN, stats + 512, stats + 768,
        nullptr, nullptr, nullptr);
    final_kernel<<<NN * FOUT / 8 / 256, b256, 0, stream>>>(h2, stats + 512, bn2g, bn2b, resb, out);
}

// Round 17
// 369.464 us; speedup vs baseline: 1.5712x; 1.0632x over previous
//
#include <hip/hip_runtime.h>
#include <hip/hip_bf16.h>
#include <math.h>

#define NN 50000
#define NE 800000
#define FIN 128
#define FOUT 256
#define EPSF 1e-5f
#define NCHUNK 196  // ceil(NN/256)

typedef __bf16 bf16x8 __attribute__((ext_vector_type(8)));
typedef __bf16 bf16x4 __attribute__((ext_vector_type(4)));
typedef __bf16 bf16x2 __attribute__((ext_vector_type(2)));
typedef float f32x4 __attribute__((ext_vector_type(4)));
typedef _Float16 f16x8 __attribute__((ext_vector_type(8)));
typedef unsigned int u32x4 __attribute__((ext_vector_type(4)));

// ---------------------------------------------------------------------------
// Fused prep: cvt x->(bf16, wid-scaled bf16, fp16) + all weight packing.
// ---------------------------------------------------------------------------
__device__ __forceinline__ void prep_b_body(const float* __restrict__ B,
                                            __bf16* __restrict__ frag, int K, int bid, int t) {
    int idx = bid * 256 + t;
    if (idx >= K * 256) return;
    int i = idx & 7, l = (idx >> 3) & 63, ct = (idx >> 9) & 15, kk = idx >> 13;
    int k = kk * 32 + (l >> 4) * 8 + i;
    int c = ct * 16 + (l & 15);
    frag[idx] = (__bf16)B[k * 256 + c];
}

__global__ void prep_all_kernel(
    const float* __restrict__ x, const float* __restrict__ wid,
    __bf16* __restrict__ xbf, __bf16* __restrict__ xw, _Float16* __restrict__ xh,
    const float* __restrict__ m1w1, const float* __restrict__ m2w1, _Float16* __restrict__ efrag,
    const float* __restrict__ fc1w, __bf16* __restrict__ bfrag1,
    const float* __restrict__ fc2w, __bf16* __restrict__ bfrag2,
    const float* __restrict__ resw, __bf16* __restrict__ bfragR)
{
    int b = blockIdx.x, t = threadIdx.x;
    if (b < 3125) {
        int idx = b * 256 + t;
        if (idx >= NN * FIN / 8) return;
        float w = wid[idx >> 4];
        float4 a = ((const float4*)x)[idx * 2 + 0];
        float4 c = ((const float4*)x)[idx * 2 + 1];
        bf16x8 v = {(__bf16)a.x, (__bf16)a.y, (__bf16)a.z, (__bf16)a.w,
                    (__bf16)c.x, (__bf16)c.y, (__bf16)c.z, (__bf16)c.w};
        bf16x8 vw = {(__bf16)(w * a.x), (__bf16)(w * a.y), (__bf16)(w * a.z), (__bf16)(w * a.w),
                     (__bf16)(w * c.x), (__bf16)(w * c.y), (__bf16)(w * c.z), (__bf16)(w * c.w)};
        f16x8 vh = {(_Float16)a.x, (_Float16)a.y, (_Float16)a.z, (_Float16)a.w,
                    (_Float16)c.x, (_Float16)c.y, (_Float16)c.z, (_Float16)c.w};
        ((bf16x8*)xbf)[idx] = v;
        ((bf16x8*)xw)[idx] = vw;
        ((f16x8*)xh)[idx] = vh;
        return;
    }
    b -= 3125;
    if (b < 32) {
        int idx = b * 256 + t;
        int i = idx & 7, l = (idx >> 3) & 63, ct = (idx >> 9) & 3, kt = idx >> 11;
        int n = l & 15, kb = l >> 4;
        int k = kt * 32 + kb * 8 + i;
        int c = ct * 16 + n;
        float w = (c < 32) ? m1w1[k * 32 + c] : m2w1[k * 32 + (c - 32)];
        efrag[idx] = (_Float16)w;
        return;
    }
    b -= 32;
    if (b < 128) { prep_b_body(fc1w, bfrag1, 128, b, t); return; }
    b -= 128;
    if (b < 256) { prep_b_body(fc1w + 128 * 256, bfrag1 + 128 * 256, 256, b, t); return; }
    b -= 256;
    if (b < 256) { prep_b_body(fc2w, bfrag2, 256, b, t); return; }
    b -= 256;
    if (b < 512) { prep_b_body(fc2w + 256 * 256, bfrag2 + 256 * 256, 512, b, t); return; }
    b -= 512;
    prep_b_body(resw, bfragR, 128, b, t);
}

// ---------------------------------------------------------------------------
// CSR build: histogram, 3-kernel exclusive scan, fill (col,row) int2.
// ---------------------------------------------------------------------------
__global__ void hist_kernel(const int* __restrict__ rowi, int* __restrict__ counts) {
    int e = blockIdx.x * 256 + threadIdx.x;
    if (e < NE) atomicAdd(&counts[rowi[e]], 1);
}

__global__ void scan1_kernel(const int* __restrict__ counts, int* __restrict__ blksum) {
    __shared__ int s[256];
    int t = threadIdx.x, idx = blockIdx.x * 256 + t;
    s[t] = (idx < NN) ? counts[idx] : 0;
    __syncthreads();
    for (int off = 128; off > 0; off >>= 1) {
        if (t < off) s[t] += s[t + off];
        __syncthreads();
    }
    if (t == 0) blksum[blockIdx.x] = s[0];
}

__global__ void scan2_kernel(const int* __restrict__ blksum, int* __restrict__ blkoff) {
    __shared__ int s[256];
    int t = threadIdx.x;
    int v = (t < NCHUNK) ? blksum[t] : 0;
    s[t] = v; __syncthreads();
    for (int off = 1; off < 256; off <<= 1) {
        int xv = (t >= off) ? s[t - off] : 0;
        __syncthreads();
        s[t] += xv;
        __syncthreads();
    }
    if (t < NCHUNK) blkoff[t] = s[t] - v;  // exclusive
}

__global__ void scan3_kernel(const int* __restrict__ counts, const int* __restrict__ blkoff,
                             int* __restrict__ row_start) {
    __shared__ int s[256];
    int t = threadIdx.x, idx = blockIdx.x * 256 + t;
    int v = (idx < NN) ? counts[idx] : 0;
    s[t] = v; __syncthreads();
    for (int off = 1; off < 256; off <<= 1) {
        int xv = (t >= off) ? s[t - off] : 0;
        __syncthreads();
        s[t] += xv;
        __syncthreads();
    }
    if (idx <= NN) row_start[idx] = s[t] - v + blkoff[blockIdx.x];
}

__global__ void fill_kernel(const int* __restrict__ rowi, const int* __restrict__ coli,
                            const int* __restrict__ row_start, int* __restrict__ cursor,
                            int2* __restrict__ perm) {
    int e = blockIdx.x * 256 + threadIdx.x;
    if (e >= NE) return;
    int r = rowi[e];
    int p = row_start[r] + atomicAdd(&cursor[r], 1);
    perm[p] = make_int2(coli[e], r);
}

// ---------------------------------------------------------------------------
// Edge MLP via fp16 MFMA over CSR-ordered edges (packed-half abs-diff).
// ---------------------------------------------------------------------------
__global__ __launch_bounds__(256) void edge_mlp_mfma(
    const _Float16* __restrict__ x, const int2* __restrict__ perm,
    const _Float16* __restrict__ fragbuf,
    const float* __restrict__ b1a, const float* __restrict__ w2a, const float* __restrict__ b2a,
    const float* __restrict__ b1b, const float* __restrict__ w2b, const float* __restrict__ b2b,
    float2* __restrict__ v12)
{
    int lane = threadIdx.x & 63;
    int gwave = (blockIdx.x * 256 + threadIdx.x) >> 6;
    int nwaves = (gridDim.x * 256) >> 6;

    f16x8 bfrag[4][4];
    const f16x8* fb = (const f16x8*)fragbuf;
#pragma unroll
    for (int kt = 0; kt < 4; kt++)
#pragma unroll
        for (int ct = 0; ct < 4; ct++)
            bfrag[kt][ct] = fb[(kt * 4 + ct) * 64 + lane];

    int n = lane & 15;
    int kb = lane >> 4;
    float b1c[4], w2c[4];
#pragma unroll
    for (int ct = 0; ct < 4; ct++) {
        int c = ct * 16 + n;
        b1c[ct] = (c < 32) ? b1a[c] : b1b[c - 32];
        w2c[ct] = (c < 32) ? w2a[c] : w2b[c - 32];
    }
    float bias2a = b2a[0], bias2b = b2b[0];
    const u32x4 amask = {0x7FFF7FFFu, 0x7FFF7FFFu, 0x7FFF7FFFu, 0x7FFF7FFFu};

    const int ngroups = NE / 16;
    for (int g = gwave; g < ngroups; g += nwaves) {
        int2 pe = perm[g * 16 + n];
        const _Float16* xr = x + (size_t)pe.y * FIN + kb * 8;
        const _Float16* xc = x + (size_t)pe.x * FIN + kb * 8;
        f32x4 acc[4] = {{0.f, 0.f, 0.f, 0.f}, {0.f, 0.f, 0.f, 0.f},
                        {0.f, 0.f, 0.f, 0.f}, {0.f, 0.f, 0.f, 0.f}};
#pragma unroll
        for (int kt = 0; kt < 4; kt++) {
            f16x8 a = *(const f16x8*)(xr + kt * 32);
            f16x8 c = *(const f16x8*)(xc + kt * 32);
            f16x8 d = a - c;
            u32x4 db = __builtin_bit_cast(u32x4, d) & amask;
            f16x8 af = __builtin_bit_cast(f16x8, db);
#pragma unroll
            for (int ct = 0; ct < 4; ct++)
                acc[ct] = __builtin_amdgcn_mfma_f32_16x16x32_f16(af, bfrag[kt][ct], acc[ct], 0, 0, 0);
        }
        float p1[4], p2[4];
#pragma unroll
        for (int r = 0; r < 4; r++) {
            float h0 = fmaxf(acc[0][r] + b1c[0], 0.f) * w2c[0];
            float h1 = fmaxf(acc[1][r] + b1c[1], 0.f) * w2c[1];
            float h2 = fmaxf(acc[2][r] + b1c[2], 0.f) * w2c[2];
            float h3 = fmaxf(acc[3][r] + b1c[3], 0.f) * w2c[3];
            p1[r] = h0 + h1;
            p2[r] = h2 + h3;
        }
#pragma unroll
        for (int off = 1; off < 16; off <<= 1)
#pragma unroll
            for (int r = 0; r < 4; r++) {
                p1[r] += __shfl_xor(p1[r], off, 64);
                p2[r] += __shfl_xor(p2[r], off, 64);
            }
        if (n == 0) {
#pragma unroll
            for (int r = 0; r < 4; r++) {
                int p = g * 16 + kb * 4 + r;
                v12[p] = make_float2(1.f / (1.f + expf(-(p1[r] + bias2a))),
                                     1.f / (1.f + expf(-(p2[r] + bias2b))));
            }
        }
    }
}

// ---------------------------------------------------------------------------
// spmm: one wave per node; 8x-unrolled gather loop.
// ---------------------------------------------------------------------------
__global__ __launch_bounds__(256) void spmm1_kernel(
    const __bf16* __restrict__ x, const int2* __restrict__ perm,
    const float2* __restrict__ v12, const int* __restrict__ row_start,
    __bf16* __restrict__ agg)
{
    int lane = threadIdx.x & 63;
    int i = blockIdx.x * 4 + (threadIdx.x >> 6);
    if (i >= NN) return;
    int f0 = lane * 2;
    float a1x = 0, a1y = 0, a2x = 0, a2y = 0;
    int p0 = row_start[i], p1 = row_start[i + 1];
    int p = p0;
    for (; p + 8 <= p1; p += 8) {
        int cc[8]; float2 vv[8]; bf16x2 ff[8];
#pragma unroll
        for (int u = 0; u < 8; u++) { cc[u] = perm[p + u].x; vv[u] = v12[p + u]; }
#pragma unroll
        for (int u = 0; u < 8; u++)
            ff[u] = *(const bf16x2*)(x + (size_t)cc[u] * FIN + f0);
#pragma unroll
        for (int u = 0; u < 8; u++) {
            float fx = (float)ff[u][0], fy = (float)ff[u][1];
            a1x += vv[u].x * fx; a1y += vv[u].x * fy;
            a2x += vv[u].y * fx; a2y += vv[u].y * fy;
        }
    }
    for (; p + 4 <= p1; p += 4) {
        int cc[4]; float2 vv[4]; bf16x2 ff[4];
#pragma unroll
        for (int u = 0; u < 4; u++) { cc[u] = perm[p + u].x; vv[u] = v12[p + u]; }
#pragma unroll
        for (int u = 0; u < 4; u++)
            ff[u] = *(const bf16x2*)(x + (size_t)cc[u] * FIN + f0);
#pragma unroll
        for (int u = 0; u < 4; u++) {
            float fx = (float)ff[u][0], fy = (float)ff[u][1];
            a1x += vv[u].x * fx; a1y += vv[u].x * fy;
            a2x += vv[u].y * fx; a2y += vv[u].y * fy;
        }
    }
    for (; p < p1; p++) {
        int c = perm[p].x;
        float2 vv = v12[p];
        bf16x2 f = *(const bf16x2*)(x + (size_t)c * FIN + f0);
        float fx = (float)f[0], fy = (float)f[1];
        a1x += vv.x * fx; a1y += vv.x * fy;
        a2x += vv.y * fx; a2y += vv.y * fy;
    }
    __bf16* ag = agg + (size_t)i * 256;
    *(bf16x2*)(ag + f0) = (bf16x2){(__bf16)a1x, (__bf16)a1y};
    *(bf16x2*)(ag + FIN + f0) = (bf16x2){(__bf16)a2x, (__bf16)a2y};
}

__global__ __launch_bounds__(256) void spmm2_kernel(
    const __bf16* __restrict__ h, const int2* __restrict__ perm,
    const float2* __restrict__ v12, const int* __restrict__ row_start,
    __bf16* __restrict__ agg)
{
    int lane = threadIdx.x & 63;
    int i = blockIdx.x * 4 + (threadIdx.x >> 6);
    if (i >= NN) return;
    int f0 = lane * 4;
    float s1x = 0, s1y = 0, s1z = 0, s1w = 0, s2x = 0, s2y = 0, s2z = 0, s2w = 0;
    int p0 = row_start[i], p1 = row_start[i + 1];
    int p = p0;
    for (; p + 8 <= p1; p += 8) {
        int cc[8]; float2 vv[8]; bf16x4 ff[8];
#pragma unroll
        for (int u = 0; u < 8; u++) { cc[u] = perm[p + u].x; vv[u] = v12[p + u]; }
#pragma unroll
        for (int u = 0; u < 8; u++)
            ff[u] = *(const bf16x4*)(h + (size_t)cc[u] * FOUT + f0);
#pragma unroll
        for (int u = 0; u < 8; u++) {
            float fx = (float)ff[u][0], fy = (float)ff[u][1];
            float fz = (float)ff[u][2], fw = (float)ff[u][3];
            s1x += vv[u].x * fx; s1y += vv[u].x * fy; s1z += vv[u].x * fz; s1w += vv[u].x * fw;
            s2x += vv[u].y * fx; s2y += vv[u].y * fy; s2z += vv[u].y * fz; s2w += vv[u].y * fw;
        }
    }
    for (; p + 4 <= p1; p += 4) {
        int cc[4]; float2 vv[4]; bf16x4 ff[4];
#pragma unroll
        for (int u = 0; u < 4; u++) { cc[u] = perm[p + u].x; vv[u] = v12[p + u]; }
#pragma unroll
        for (int u = 0; u < 4; u++)
            ff[u] = *(const bf16x4*)(h + (size_t)cc[u] * FOUT + f0);
#pragma unroll
        for (int u = 0; u < 4; u++) {
            float fx = (float)ff[u][0], fy = (float)ff[u][1];
            float fz = (float)ff[u][2], fw = (float)ff[u][3];
            s1x += vv[u].x * fx; s1y += vv[u].x * fy; s1z += vv[u].x * fz; s1w += vv[u].x * fw;
            s2x += vv[u].y * fx; s2y += vv[u].y * fy; s2z += vv[u].y * fz; s2w += vv[u].y * fw;
        }
    }
    for (; p < p1; p++) {
        int c = perm[p].x;
        float2 vv = v12[p];
        bf16x4 f = *(const bf16x4*)(h + (size_t)c * FOUT + f0);
        float fx = (float)f[0], fy = (float)f[1], fz = (float)f[2], fw = (float)f[3];
        s1x += vv.x * fx; s1y += vv.x * fy; s1z += vv.x * fz; s1w += vv.x * fw;
        s2x += vv.y * fx; s2y += vv.y * fy; s2z += vv.y * fz; s2w += vv.y * fw;
    }
    __bf16* ag = agg + (size_t)i * 512;
    *(bf16x4*)(ag + f0) = (bf16x4){(__bf16)s1x, (__bf16)s1y, (__bf16)s1z, (__bf16)s1w};
    *(bf16x4*)(ag + FOUT + f0) = (bf16x4){(__bf16)s2x, (__bf16)s2y, (__bf16)s2z, (__bf16)s2w};
}

// ---------------------------------------------------------------------------
// Persistent-panel bf16 MFMA GEMM, compile-time K, bounded unroll, 12 waves,
// XCD-coscheduled panels (round 14, validated: FETCH 150->39MB). NEW: rows
// partitioned into 64 BALANCED contiguous ranges (~M/64 each); waves whose
// 48-row slab lies beyond the range end SKIP the K-loop entirely (legal:
// barrier-free tile body). Per-block wave-work 24 -> ~17 wave-tiles.
// ---------------------------------------------------------------------------
template<int NKA, int NKB>
__device__ __forceinline__ void gemm_core(
    const __bf16* __restrict__ Aa, const __bf16* __restrict__ Ab,
    const __bf16* __restrict__ Bfrag,
    const float* __restrict__ bias, __bf16* __restrict__ C, int M,
    float* __restrict__ colsum, float* __restrict__ colsq,
    __bf16* bs, float* lsum, float* lsq, int bid, int t)
{
    constexpr int NK = NKA + NKB;
    constexpr int KA = NKA * 32;
    constexpr int KB = NKB * 32;
    int lane = t & 63, w = t >> 6;
    // XCD-coscheduled decode: 4 panels (q) of row-group rgrp share bid&7.
    int xcd = bid & 7;
    int q = (bid >> 3) & 3;
    int rgrp = ((bid >> 5) << 3) | xcd;   // [0,64)
    int n = lane & 15, kb = lane >> 4;
    int rbeg  = (int)(((long long)rgrp * M) / 64);
    int rendg = (int)(((long long)(rgrp + 1) * M) / 64);

    // ---- stage the full-K 64-col B panel (once) ----
    int nseg = NK * 4;
    for (int s = w; s < nseg; s += 12) {
        const __bf16* src = Bfrag + (((size_t)(s >> 2) * 16 + q * 4 + (s & 3)) * 512) + lane * 8;
        __builtin_amdgcn_global_load_lds(
            (const __attribute__((address_space(1))) void*)src,
            (__attribute__((address_space(3))) void*)(bs + s * 512),
            16, 0, 0);
    }
    float bv[4];
#pragma unroll
    for (int ct = 0; ct < 4; ct++) bv[ct] = bias ? bias[q * 64 + ct * 16 + n] : 0.f;
    __syncthreads();                      // DMA drained; panel resident

    float psum[4] = {0.f, 0.f, 0.f, 0.f}, psq[4] = {0.f, 0.f, 0.f, 0.f};

    for (int tile0 = rbeg; tile0 < rendg; tile0 += 576) {
        int rend = (tile0 + 576 < rendg) ? tile0 + 576 : rendg;
        int rowbase = tile0 + w * 48;
        if (rowbase >= rend) continue;    // wave-skip (no barriers in body)
        const __bf16 *pA[3], *pB[3];
#pragma unroll
        for (int f = 0; f < 3; f++) {
            int r = rowbase + f * 16 + n; if (r > M - 1) r = M - 1;
            pA[f] = Aa + (size_t)r * KA + kb * 8;
            pB[f] = (NKB > 0 && Ab) ? (Ab + (size_t)r * KB + kb * 8) : pA[f];
        }
        f32x4 acc[3][4];
#pragma unroll
        for (int f = 0; f < 3; f++)
#pragma unroll
            for (int ct = 0; ct < 4; ct++) acc[f][ct] = (f32x4){0.f, 0.f, 0.f, 0.f};

#pragma unroll 4
        for (int kk = 0; kk < NKA; kk++) {
            bf16x8 a[3];
#pragma unroll
            for (int f = 0; f < 3; f++) a[f] = *(const bf16x8*)(pA[f] + kk * 32);
            const __bf16* bbase = bs + kk * 2048 + lane * 8;
#pragma unroll
            for (int ct = 0; ct < 4; ct++) {
                bf16x8 bf = *(const bf16x8*)(bbase + ct * 512);
#pragma unroll
                for (int f = 0; f < 3; f++)
                    acc[f][ct] = __builtin_amdgcn_mfma_f32_16x16x32_bf16(a[f], bf, acc[f][ct], 0, 0, 0);
            }
        }
#pragma unroll 4
        for (int kk = 0; kk < NKB; kk++) {
            bf16x8 a[3];
#pragma unroll
            for (int f = 0; f < 3; f++) a[f] = *(const bf16x8*)(pB[f] + kk * 32);
            const __bf16* bbase = bs + (NKA + kk) * 2048 + lane * 8;
#pragma unroll
            for (int ct = 0; ct < 4; ct++) {
                bf16x8 bf = *(const bf16x8*)(bbase + ct * 512);
#pragma unroll
                for (int f = 0; f < 3; f++)
                    acc[f][ct] = __builtin_amdgcn_mfma_f32_16x16x32_bf16(a[f], bf, acc[f][ct], 0, 0, 0);
            }
        }

#pragma unroll
        for (int f = 0; f < 3; f++) {
            int rbase = rowbase + f * 16 + kb * 4;
#pragma unroll
            for (int ct = 0; ct < 4; ct++) {
                int col = q * 64 + ct * 16 + n;
#pragma unroll
                for (int r = 0; r < 4; r++) {
                    int gm = rbase + r;
                    if (gm < rend) {
                        float v = acc[f][ct][r] + bv[ct];
                        C[(size_t)gm * 256 + col] = (__bf16)v;
                        psum[ct] += v; psq[ct] += v * v;
                    }
                }
            }
        }
    }

    if (colsum) {
        __syncthreads();
        if (t < 64) { lsum[t] = 0.f; lsq[t] = 0.f; }
        __syncthreads();
#pragma unroll
        for (int ct = 0; ct < 4; ct++) {
            float ps = psum[ct], pq = psq[ct];
            ps += __shfl_xor(ps, 16, 64); pq += __shfl_xor(pq, 16, 64);
            ps += __shfl_xor(ps, 32, 64); pq += __shfl_xor(pq, 32, 64);
            if (lane < 16) {
                atomicAdd(&lsum[ct * 16 + n], ps);
                atomicAdd(&lsq[ct * 16 + n], pq);
            }
        }
        __syncthreads();
        if (t < 64) {
            atomicAdd(&colsum[q * 64 + t], lsum[t]);
            atomicAdd(&colsq[q * 64 + t], lsq[t]);
        }
    }
}

template<int NKA, int NKB, int RNKA>
__global__ __launch_bounds__(768) void gemm_persist(
    const __bf16* __restrict__ Aa, const __bf16* __restrict__ Ab,
    const __bf16* __restrict__ Bfrag,
    const float* __restrict__ bias, __bf16* __restrict__ C, int M,
    float* __restrict__ colsum, float* __restrict__ colsq,
    const __bf16* __restrict__ Ra, const __bf16* __restrict__ RBfrag,
    __bf16* __restrict__ RC)
{
    constexpr int NKMAX = (NKA + NKB > RNKA) ? (NKA + NKB) : RNKA;
    __shared__ __bf16 bs[NKMAX * 2048];
    __shared__ float lsum[64], lsq[64];
    int bid = blockIdx.x, t = threadIdx.x;
    if (bid >= 256) {
        if constexpr (RNKA > 0)
            gemm_core<RNKA, 0>(Ra, nullptr, RBfrag, nullptr, RC, M,
                               nullptr, nullptr, bs, lsum, lsq, bid - 256, t);
        return;
    }
    gemm_core<NKA, NKB>(Aa, Ab, Bfrag, bias, C, M, colsum, colsq, bs, lsum, lsq, bid, t);
}

// ---------------------------------------------------------------------------
// BN apply (+relu) bf16->bf16 (plain + wid-scaled), and final BN+res+relu.
// ---------------------------------------------------------------------------
__device__ __forceinline__ float bn1c(float v, float s, float q, float g, float b) {
    const float invn = 1.0f / (float)NN;
    float mu = s * invn;
    float var = q * invn - mu * mu;
    float r = rsqrtf(var + EPSF);
    return (v - mu) * r * g + b;
}

__global__ __launch_bounds__(256) void bn_relu_kernel(
    const __bf16* __restrict__ h, const float* __restrict__ stats,
    const float* __restrict__ g, const float* __restrict__ b,
    const float* __restrict__ wid,
    __bf16* __restrict__ o, __bf16* __restrict__ ow)
{
    size_t idx = (size_t)blockIdx.x * 256 + threadIdx.x;
    int j = ((int)idx & 31) * 8;
    float wv = wid[idx >> 5];
    bf16x8 v = ((const bf16x8*)h)[idx];
    bf16x8 r, rw;
#pragma unroll
    for (int u = 0; u < 8; u++) {
        float val = fmaxf(bn1c((float)v[u], stats[j + u], stats[256 + j + u], g[j + u], b[j + u]), 0.f);
        r[u] = (__bf16)val;
        rw[u] = (__bf16)(wv * val);
    }
    ((bf16x8*)o)[idx] = r;
    ((bf16x8*)ow)[idx] = rw;
}

__global__ __launch_bounds__(256) void final_kernel(
    const __bf16* __restrict__ h2, const float* __restrict__ stats,
    const float* __restrict__ g, const float* __restrict__ b,
    const __bf16* __restrict__ resb, float* __restrict__ o)
{
    size_t idx = (size_t)blockIdx.x * 256 + threadIdx.x;
    int j = ((int)idx & 31) * 8;
    bf16x8 v = ((const bf16x8*)h2)[idx];
    bf16x8 rr = ((const bf16x8*)resb)[idx];
    float r[8];
#pragma unroll
    for (int u = 0; u < 8; u++)
        r[u] = fmaxf(bn1c((float)v[u], stats[j + u], stats[256 + j + u], g[j + u], b[j + u]) + (float)rr[u], 0.f);
    float4 o0 = {r[0], r[1], r[2], r[3]}, o1 = {r[4], r[5], r[6], r[7]};
    ((float4*)o)[idx * 2 + 0] = o0;
    ((float4*)o)[idx * 2 + 1] = o1;
}

// ---------------------------------------------------------------------------
extern "C" void kernel_launch(void* const* d_in, const int* in_sizes, int n_in,
                              void* d_out, int out_size, void* d_ws, size_t ws_size,
                              hipStream_t stream)
{
    (void)in_sizes; (void)n_in; (void)out_size; (void)ws_size;
    const float* x    = (const float*)d_in[0];
    const float* wid  = (const float*)d_in[1];
    const int*   widx = (const int*)d_in[2];
    const float* m1w1 = (const float*)d_in[4];
    const float* m1b1 = (const float*)d_in[5];
    const float* m1w2 = (const float*)d_in[6];
    const float* m1b2 = (const float*)d_in[7];
    const float* m2w1 = (const float*)d_in[8];
    const float* m2b1 = (const float*)d_in[9];
    const float* m2w2 = (const float*)d_in[10];
    const float* m2b2 = (const float*)d_in[11];
    const float* fc1w = (const float*)d_in[12];
    const float* fc1b = (const float*)d_in[13];
    const float* bn1g = (const float*)d_in[14];
    const float* bn1b = (const float*)d_in[15];
    const float* fc2w = (const float*)d_in[16];
    const float* fc2b = (const float*)d_in[17];
    const float* bn2g = (const float*)d_in[18];
    const float* bn2b = (const float*)d_in[19];
    const float* resw = (const float*)d_in[20];
    float* out = (float*)d_out;

    char* ws = (char*)d_ws;
    __bf16* xbf   = (__bf16*)(ws);                    // 12.8 MB
    __bf16* xw    = (__bf16*)(ws + 12800000);         // 12.8 MB (wid ⊙ x)
    int2*   perm  = (int2*)(ws + 25600000);           // 6.4 MB
    float2* v12   = (float2*)(ws + 32000000);         // 6.4 MB
    __bf16* agg1s = (__bf16*)(ws + 38400000);         // [NN,256] 25.6 MB
    __bf16* agg2s = (__bf16*)(ws + 64000000);         // [NN,512] 51.2 MB
    __bf16* h1    = (__bf16*)(ws + 115200000);        // 25.6 MB (h2 overlay)
    __bf16* h2    = h1;
    __bf16* hbn   = (__bf16*)(ws + 140800000);        // 25.6 MB
    __bf16* hw    = (__bf16*)(ws + 166400000);        // 25.6 MB (wid ⊙ hbn)
    __bf16* resb  = (__bf16*)(ws + 192000000);        // 25.6 MB
    const size_t offS = 217600000;
    int* row_start = (int*)(ws + offS);               // 200064 B
    int* cursor    = (int*)(ws + offS + 200064);      // 200064 B
    int* blksum    = (int*)(ws + offS + 400128);
    int* blkoff    = (int*)(ws + offS + 401152);
    float* stats   = (float*)(ws + offS + 402176);    // 1024 floats
    _Float16* efrag = (_Float16*)(ws + offS + 406272);  // 16 KB
    __bf16* bfrag1 = (__bf16*)(ws + offS + 422656);   // 384*256*2 = 196608
    __bf16* bfrag2 = (__bf16*)(ws + offS + 619264);   // 768*256*2 = 393216
    __bf16* bfragR = (__bf16*)(ws + offS + 1012480);  // 128*256*2 = 65536
    _Float16* xh   = (_Float16*)(ws + offS + 1078016); // 12.8 MB fp16 x

    dim3 b256(256);

    // 0) fused conversions + weight packing (1 dispatch)
    prep_all_kernel<<<3125 + 32 + 128 + 256 + 256 + 512 + 128, b256, 0, stream>>>(
        x, wid, xbf, xw, xh, m1w1, m2w1, efrag, fc1w, bfrag1, fc2w, bfrag2, resw, bfragR);

    // 1) CSR build (indices only)
    hipMemsetAsync(cursor, 0, NN * 4, stream);
    hist_kernel<<<NE / 256, b256, 0, stream>>>(widx, cursor);
    scan1_kernel<<<NCHUNK, b256, 0, stream>>>(cursor, blksum);
    scan2_kernel<<<1, b256, 0, stream>>>(blksum, blkoff);
    scan3_kernel<<<NCHUNK, b256, 0, stream>>>(cursor, blkoff, row_start);
    hipMemsetAsync(cursor, 0, NN * 4, stream);
    fill_kernel<<<NE / 256, b256, 0, stream>>>(widx, widx + NE, row_start, cursor, perm);

    // 2) edge MLP over CSR order -> v12
    edge_mlp_mfma<<<2500, b256, 0, stream>>>(xh, perm, efrag,
        m1b1, m1w2, m1b2, m2b1, m2w2, m2b2, v12);

    // 3) conv1 (+ res GEMM fused, blocks 256..511)
    spmm1_kernel<<<NN / 4, b256, 0, stream>>>(xbf, perm, v12, row_start, agg1s);
    hipMemsetAsync(stats, 0, 1024 * 4, stream);
    gemm_persist<4, 8, 4><<<512, dim3(768), 0, stream>>>(
        xw, agg1s, bfrag1, fc1b, h1, NN, stats, stats + 256,
        xbf, bfragR, resb);
    bn_relu_kernel<<<NN * FOUT / 8 / 256, b256, 0, stream>>>(h1, stats, bn1g, bn1b, wid, hbn, hw);

    // 4) conv2
    spmm2_kernel<<<NN / 4, b256, 0, stream>>>(hbn, perm, v12, row_start, agg2s);
    gemm_persist<8, 16, 0><<<256, dim3(768), 0, stream>>>(
        hw, agg2s, bfrag2, fc2b, h2, NN, stats + 512, stats + 768,
        nullptr, nullptr, nullptr);
    final_kernel<<<NN * FOUT / 8 / 256, b256, 0, stream>>>(h2, stats + 512, bn2g, bn2b, resb, out);
}